// Round 2
// baseline (184.836 us; speedup 1.0000x reference)
//
#include <hip/hip_runtime.h>

#define B_    4
#define L_    2048
#define DIN   256
#define E_    16
#define M_    768
#define ROWS  (L_ + 1)      // 2049 (cls + L)
#define NTOK  (B_ * L_)     // 8192

// ---------------------------------------------------------------------------
// Kernel A: bucket unmasked tokens by expert id.
// ws layout: int counts[16]; int bucket[16][NTOK]
// ---------------------------------------------------------------------------
__global__ void bucket_k(const int* __restrict__ sid,
                         const int* __restrict__ mask,
                         int* __restrict__ counts,
                         int* __restrict__ bucket) {
    int i = blockIdx.x * blockDim.x + threadIdx.x;
    if (i >= NTOK) return;
    if (mask[i] != 0) {
        int e = sid[i];
        int slot = atomicAdd(&counts[e], 1);   // device-scope by default
        bucket[e * NTOK + slot] = i;
    }
}

// ---------------------------------------------------------------------------
// Kernel B: write ALL output rows = table sums (tokens contribution added by
// kernel C afterwards). Also writes attn_keep as 0.0/1.0 floats.
// One block per output row (B*ROWS rows), 256 threads, 3 floats each.
// ---------------------------------------------------------------------------
__global__ void tables_k(const float* __restrict__ cls_content,
                         const float* __restrict__ pos_tab,
                         const float* __restrict__ id_tab,
                         const float* __restrict__ mod_tab,
                         const float* __restrict__ role_tab,
                         const int* __restrict__ pos,
                         const int* __restrict__ sid,
                         const int* __restrict__ mod,
                         const int* __restrict__ role,
                         const int* __restrict__ mask,
                         float* __restrict__ out,
                         float* __restrict__ attn) {
    int r = blockIdx.x;              // 0 .. B*ROWS-1
    int b = r / ROWS;
    int p = r % ROWS;
    int tid = threadIdx.x;
    float* orow = out + (size_t)r * M_;

    if (p == 0) {
        // cls row: cls_content + pos_tab[0] + id_tab[E]
#pragma unroll
        for (int j = 0; j < 3; ++j) {
            int m = tid + 256 * j;
            orow[m] = cls_content[m] + pos_tab[m] + id_tab[E_ * M_ + m];
        }
        if (tid == 0) attn[r] = 1.0f;
    } else {
        int idx = b * L_ + (p - 1);
        const float* pr = pos_tab  + (size_t)pos[idx]  * M_;
        const float* ir = id_tab   + (size_t)sid[idx]  * M_;
        const float* mr = mod_tab  + (size_t)mod[idx]  * M_;
        const float* rr = role_tab + (size_t)role[idx] * M_;
#pragma unroll
        for (int j = 0; j < 3; ++j) {
            int m = tid + 256 * j;
            orow[m] = pr[m] + ir[m] + mr[m] + rr[m];
        }
        if (tid == 0) attn[r] = (mask[idx] != 0) ? 1.0f : 0.0f;
    }
}

// ---------------------------------------------------------------------------
// Kernel C: grouped expert projection. Block = (tile of 16 same-expert
// tokens) x (expert). 256 threads; thread owns m = tid, tid+256, tid+512.
// fp32 FMA, W reads coalesced along M, emb tile staged in LDS.
// Adds (proj + bias) into rows pre-written by tables_k.
// ---------------------------------------------------------------------------
__launch_bounds__(256)
__global__ void proj_k(const float* __restrict__ emb,
                       const float* __restrict__ W,
                       const float* __restrict__ bias,
                       const int* __restrict__ counts,
                       const int* __restrict__ bucket,
                       float* __restrict__ out) {
    const int e = blockIdx.y;
    const int cnt = counts[e];
    const int t0 = blockIdx.x * 16;
    if (t0 >= cnt) return;
    const int k = min(16, cnt - t0);
    const int tid = threadIdx.x;

    __shared__ float es[16][DIN];
    __shared__ int ts[16];

    if (tid < 16) ts[tid] = (tid < k) ? bucket[e * NTOK + t0 + tid] : -1;
    __syncthreads();

#pragma unroll
    for (int i = 0; i < 16; ++i) {
        int t = ts[i];
        es[i][tid] = (t >= 0) ? emb[(size_t)t * DIN + tid] : 0.0f;
    }
    __syncthreads();

    float acc[16][3];
#pragma unroll
    for (int i = 0; i < 16; ++i)
#pragma unroll
        for (int j = 0; j < 3; ++j) acc[i][j] = 0.0f;

    const float* Wp = W + (size_t)e * DIN * M_;

    for (int d0 = 0; d0 < DIN; d0 += 4) {
        float w[4][3];
#pragma unroll
        for (int dd = 0; dd < 4; ++dd)
#pragma unroll
            for (int j = 0; j < 3; ++j)
                w[dd][j] = Wp[(size_t)(d0 + dd) * M_ + tid + 256 * j];

#pragma unroll
        for (int i = 0; i < 16; ++i) {
            float4 ev = *reinterpret_cast<const float4*>(&es[i][d0]);
#pragma unroll
            for (int j = 0; j < 3; ++j) {
                acc[i][j] = fmaf(ev.x, w[0][j], acc[i][j]);
                acc[i][j] = fmaf(ev.y, w[1][j], acc[i][j]);
                acc[i][j] = fmaf(ev.z, w[2][j], acc[i][j]);
                acc[i][j] = fmaf(ev.w, w[3][j], acc[i][j]);
            }
        }
    }

    float bj[3];
#pragma unroll
    for (int j = 0; j < 3; ++j) bj[j] = bias[e * M_ + tid + 256 * j];

    for (int i = 0; i < k; ++i) {
        int t = ts[i];
        int bb = t / L_;
        int ll = t % L_;
        float* orow = out + ((size_t)bb * ROWS + ll + 1) * M_;
#pragma unroll
        for (int j = 0; j < 3; ++j) {
            int m = tid + 256 * j;
            orow[m] += acc[i][j] + bj[j];
        }
    }
}

// ---------------------------------------------------------------------------
extern "C" void kernel_launch(void* const* d_in, const int* in_sizes, int n_in,
                              void* d_out, int out_size, void* d_ws, size_t ws_size,
                              hipStream_t stream) {
    const float* emb      = (const float*)d_in[0];
    const float* W        = (const float*)d_in[1];
    const float* bias     = (const float*)d_in[2];
    const float* cls      = (const float*)d_in[3];
    const float* pos_tab  = (const float*)d_in[4];
    const float* id_tab   = (const float*)d_in[5];
    const float* mod_tab  = (const float*)d_in[6];
    const float* role_tab = (const float*)d_in[7];
    const int*   pos      = (const int*)d_in[8];
    const int*   sid      = (const int*)d_in[9];
    const int*   mod      = (const int*)d_in[10];
    const int*   role     = (const int*)d_in[11];
    const int*   mask     = (const int*)d_in[12];

    float* out  = (float*)d_out;
    float* attn = out + (size_t)B_ * ROWS * M_;   // 6,294,528 floats in

    int* counts = (int*)d_ws;
    int* bucket = counts + 16;

    hipMemsetAsync(d_ws, 0, 16 * sizeof(int), stream);

    bucket_k<<<(NTOK + 255) / 256, 256, 0, stream>>>(sid, mask, counts, bucket);

    tables_k<<<B_ * ROWS, 256, 0, stream>>>(cls, pos_tab, id_tab, mod_tab,
                                            role_tab, pos, sid, mod, role,
                                            mask, out, attn);

    dim3 gC(NTOK / 16, E_);   // early-exit past per-expert count
    proj_k<<<gC, 256, 0, stream>>>(emb, W, bias, counts, bucket, out);
}

// Round 3
// 124.653 us; speedup vs baseline: 1.4828x; 1.4828x over previous
//
#include <hip/hip_runtime.h>

#define B_    4
#define L_    2048
#define DIN   256
#define E_    16
#define M_    768
#define ROWS  (L_ + 1)      // 2049 (cls + L)
#define NTOK  (B_ * L_)     // 8192

// ---------------------------------------------------------------------------
// Kernel A: bucket unmasked tokens by expert id.
// ws layout: int counts[16]; int bucket[16][NTOK]
// ---------------------------------------------------------------------------
__global__ void bucket_k(const int* __restrict__ sid,
                         const int* __restrict__ mask,
                         int* __restrict__ counts,
                         int* __restrict__ bucket) {
    int i = blockIdx.x * blockDim.x + threadIdx.x;
    if (i >= NTOK) return;
    if (mask[i] != 0) {
        int e = sid[i];
        int slot = atomicAdd(&counts[e], 1);   // device-scope by default
        bucket[e * NTOK + slot] = i;
    }
}

// ---------------------------------------------------------------------------
// Kernel B: write ALL output rows = table sums. attn_keep as 0.0/1.0 floats.
// ---------------------------------------------------------------------------
__global__ void tables_k(const float* __restrict__ cls_content,
                         const float* __restrict__ pos_tab,
                         const float* __restrict__ id_tab,
                         const float* __restrict__ mod_tab,
                         const float* __restrict__ role_tab,
                         const int* __restrict__ pos,
                         const int* __restrict__ sid,
                         const int* __restrict__ mod,
                         const int* __restrict__ role,
                         const int* __restrict__ mask,
                         float* __restrict__ out,
                         float* __restrict__ attn) {
    int r = blockIdx.x;              // 0 .. B*ROWS-1
    int b = r / ROWS;
    int p = r % ROWS;
    int tid = threadIdx.x;
    float* orow = out + (size_t)r * M_;

    if (p == 0) {
#pragma unroll
        for (int j = 0; j < 3; ++j) {
            int m = tid + 256 * j;
            orow[m] = cls_content[m] + pos_tab[m] + id_tab[E_ * M_ + m];
        }
        if (tid == 0) attn[r] = 1.0f;
    } else {
        int idx = b * L_ + (p - 1);
        const float* pr = pos_tab  + (size_t)pos[idx]  * M_;
        const float* ir = id_tab   + (size_t)sid[idx]  * M_;
        const float* mr = mod_tab  + (size_t)mod[idx]  * M_;
        const float* rr = role_tab + (size_t)role[idx] * M_;
#pragma unroll
        for (int j = 0; j < 3; ++j) {
            int m = tid + 256 * j;
            orow[m] = pr[m] + ir[m] + mr[m] + rr[m];
        }
        if (tid == 0) attn[r] = (mask[idx] != 0) ? 1.0f : 0.0f;
    }
}

// ---------------------------------------------------------------------------
// Kernel C: grouped expert projection.
// Grid (16 tile-slots [stride loop], 16 experts, 3 m-chunks).
// Block: 256 threads, thread owns ONE m column (chunk*256 + tid), 16 tokens
// per tile -> acc[16] in registers (ALL indices compile-time: no scratch).
// ---------------------------------------------------------------------------
__launch_bounds__(256)
__global__ void proj_k(const float* __restrict__ emb,
                       const float* __restrict__ W,
                       const float* __restrict__ bias,
                       const int* __restrict__ counts,
                       const int* __restrict__ bucket,
                       float* __restrict__ out) {
    const int e     = blockIdx.y;
    const int chunk = blockIdx.z;           // 0..2
    const int cnt   = counts[e];
    const int ntile = (cnt + 15) >> 4;
    const int tid   = threadIdx.x;
    const int m     = chunk * 256 + tid;

    __shared__ float es[16][DIN];
    __shared__ int   ts[16];

    const float* Wp = W + (size_t)e * DIN * M_ + m;
    const float  bj = bias[e * M_ + m];

    for (int tile = blockIdx.x; tile < ntile; tile += gridDim.x) {
        const int t0 = tile * 16;
        const int k  = min(16, cnt - t0);

        __syncthreads();   // protect es/ts from previous iteration's readers
        if (tid < 16) ts[tid] = (tid < k) ? bucket[e * NTOK + t0 + tid] : -1;
        __syncthreads();
#pragma unroll
        for (int i = 0; i < 16; ++i) {
            int t = ts[i];
            es[i][tid] = (t >= 0) ? emb[(size_t)t * DIN + tid] : 0.0f;
        }
        __syncthreads();

        float acc[16];
#pragma unroll
        for (int i = 0; i < 16; ++i) acc[i] = 0.0f;

        for (int d0 = 0; d0 < DIN; d0 += 8) {
            float w[8];
#pragma unroll
            for (int dd = 0; dd < 8; ++dd)
                w[dd] = Wp[(size_t)(d0 + dd) * M_];

#pragma unroll
            for (int i = 0; i < 16; ++i) {
                float4 e0 = *reinterpret_cast<const float4*>(&es[i][d0]);
                float4 e1 = *reinterpret_cast<const float4*>(&es[i][d0 + 4]);
                acc[i] = fmaf(e0.x, w[0], acc[i]);
                acc[i] = fmaf(e0.y, w[1], acc[i]);
                acc[i] = fmaf(e0.z, w[2], acc[i]);
                acc[i] = fmaf(e0.w, w[3], acc[i]);
                acc[i] = fmaf(e1.x, w[4], acc[i]);
                acc[i] = fmaf(e1.y, w[5], acc[i]);
                acc[i] = fmaf(e1.z, w[6], acc[i]);
                acc[i] = fmaf(e1.w, w[7], acc[i]);
            }
        }

        // Epilogue: STATIC unroll with guard so acc stays in registers.
#pragma unroll
        for (int i = 0; i < 16; ++i) {
            if (i < k) {
                int t  = ts[i];
                int bb = t >> 11;            // / L_ (2048)
                int ll = t & (L_ - 1);
                out[((size_t)bb * ROWS + ll + 1) * M_ + m] += acc[i] + bj;
            }
        }
    }
}

// ---------------------------------------------------------------------------
extern "C" void kernel_launch(void* const* d_in, const int* in_sizes, int n_in,
                              void* d_out, int out_size, void* d_ws, size_t ws_size,
                              hipStream_t stream) {
    const float* emb      = (const float*)d_in[0];
    const float* W        = (const float*)d_in[1];
    const float* bias     = (const float*)d_in[2];
    const float* cls      = (const float*)d_in[3];
    const float* pos_tab  = (const float*)d_in[4];
    const float* id_tab   = (const float*)d_in[5];
    const float* mod_tab  = (const float*)d_in[6];
    const float* role_tab = (const float*)d_in[7];
    const int*   pos      = (const int*)d_in[8];
    const int*   sid      = (const int*)d_in[9];
    const int*   mod      = (const int*)d_in[10];
    const int*   role     = (const int*)d_in[11];
    const int*   mask     = (const int*)d_in[12];

    float* out  = (float*)d_out;
    float* attn = out + (size_t)B_ * ROWS * M_;

    int* counts = (int*)d_ws;
    int* bucket = counts + 16;

    hipMemsetAsync(d_ws, 0, 16 * sizeof(int), stream);

    bucket_k<<<(NTOK + 255) / 256, 256, 0, stream>>>(sid, mask, counts, bucket);

    tables_k<<<B_ * ROWS, 256, 0, stream>>>(cls, pos_tab, id_tab, mod_tab,
                                            role_tab, pos, sid, mod, role,
                                            mask, out, attn);

    dim3 gC(16, E_, 3);
    proj_k<<<gC, 256, 0, stream>>>(emb, W, bias, counts, bucket, out);
}